// Round 2
// baseline (518.183 us; speedup 1.0000x reference)
//
#include <hip/hip_runtime.h>
#include <hip/hip_bf16.h>

#define N_ROWS 8192
#define F_DIM  256

typedef __bf16 bf16x8_t __attribute__((ext_vector_type(8)));
typedef float  f32x4_t  __attribute__((ext_vector_type(4)));

static __device__ __forceinline__ unsigned short f2bf(float x) {
    union { __hip_bfloat16 h; unsigned short u; } c;
    c.h = __float2bfloat16(x);   // RNE
    return c.u;
}
static __device__ __forceinline__ unsigned pk2(float lo, float hi) {
    return (unsigned)f2bf(lo) | ((unsigned)f2bf(hi) << 16);
}

// async global->LDS, 16B per lane; LDS dst = wave-uniform base + lane*16
static __device__ __forceinline__ void gload16(const unsigned short* g, unsigned short* s) {
    __builtin_amdgcn_global_load_lds((const __attribute__((address_space(1))) void*)g,
                                     (__attribute__((address_space(3))) void*)s, 16, 0, 0);
}

// ---------------------------------------------------------------------------
// K0: W [256][256] fp32 -> bf16, swizzled Ws[kb][n][kc]  (kb=k>>5, kc=k&31)
// B-fragment (lane: n=l&15, k=q*8+j) is one contiguous 16B load.
// ---------------------------------------------------------------------------
__global__ __launch_bounds__(256) void wconv_kernel(const float* __restrict__ W,
                                                    unsigned short* __restrict__ Ws) {
    const int kb = blockIdx.x;            // 8 blocks of 32 k-rows
    const int t  = threadIdx.x;
    __shared__ float wt[32][257];
    const int r = t >> 3, g = t & 7;
    const float* src = W + (kb * 32 + r) * F_DIM + g * 32;
#pragma unroll
    for (int i = 0; i < 8; ++i) {
        float4 v = *(const float4*)(src + i * 4);
        wt[r][g * 32 + i * 4 + 0] = v.x;
        wt[r][g * 32 + i * 4 + 1] = v.y;
        wt[r][g * 32 + i * 4 + 2] = v.z;
        wt[r][g * 32 + i * 4 + 3] = v.w;
    }
    __syncthreads();
    unsigned o[16];
#pragma unroll
    for (int k = 0; k < 32; k += 2) o[k >> 1] = pk2(wt[k][t], wt[k + 1][t]);
    uint4* dst = (uint4*)(Ws + kb * 8192 + t * 32);
#pragma unroll
    for (int i = 0; i < 4; ++i) dst[i] = make_uint4(o[4*i], o[4*i+1], o[4*i+2], o[4*i+3]);
}

// ---------------------------------------------------------------------------
// K1: per 32-row band: rowsum(A) -> d; write Abf = bf16(A) row-major;
// Xh = d*H -> bf16 swizzled [kb][n][kc].  Reads 1 MB A, writes 0.5 MB per blk.
// ---------------------------------------------------------------------------
__global__ __launch_bounds__(1024) void sumconv_kernel(const float* __restrict__ A,
                                                       const float* __restrict__ H,
                                                       float* __restrict__ dvec,
                                                       unsigned short* __restrict__ Abf,
                                                       unsigned short* __restrict__ Xh) {
    const int kb = blockIdx.x;            // 256 blocks, 32 rows each
    const int t  = threadIdx.x;
    __shared__ float psum[32][33];
    __shared__ float dl[32];
    __shared__ float ht[32][257];

    const int r = t >> 5, g = t & 31;     // 32 threads per row
    const int row = kb * 32 + r;
    const float* arow = A + (size_t)row * N_ROWS;
    unsigned short* aout = Abf + (size_t)row * N_ROWS;
    float s0 = 0.f, s1 = 0.f, s2 = 0.f, s3 = 0.f;
#pragma unroll 8
    for (int i = 0; i < 64; ++i) {
        const int e = (i * 32 + g) * 4;
        float4 v = *(const float4*)(arow + e);
        s0 += v.x; s1 += v.y; s2 += v.z; s3 += v.w;
        uint2 p = make_uint2(pk2(v.x, v.y), pk2(v.z, v.w));
        *(uint2*)(aout + e) = p;
    }
    psum[r][g] = (s0 + s1) + (s2 + s3);
    __syncthreads();
    if (t < 32) {
        float s = 0.f;
#pragma unroll
        for (int i = 0; i < 32; ++i) s += psum[t][i];
        float d = 1.0f / sqrtf(s);
        dl[t] = d;
        dvec[kb * 32 + t] = d;
    }
    __syncthreads();
    {   // load H band pre-scaled by d_row into LDS
        const int hr = t >> 5, hg = t & 31;
        const float* hsrc = H + (size_t)(kb * 32 + hr) * F_DIM + hg * 8;
        float4 v0 = ((const float4*)hsrc)[0];
        float4 v1 = ((const float4*)hsrc)[1];
        const float d = dl[hr];
        ht[hr][hg * 8 + 0] = v0.x * d;
        ht[hr][hg * 8 + 1] = v0.y * d;
        ht[hr][hg * 8 + 2] = v0.z * d;
        ht[hr][hg * 8 + 3] = v0.w * d;
        ht[hr][hg * 8 + 4] = v1.x * d;
        ht[hr][hg * 8 + 5] = v1.y * d;
        ht[hr][hg * 8 + 6] = v1.z * d;
        ht[hr][hg * 8 + 7] = v1.w * d;
    }
    __syncthreads();
    // transpose-read: thread -> (n = t>>2, quarter q = t&3), write 16 B
    const int n = t >> 2, q = t & 3;
    unsigned o[4];
#pragma unroll
    for (int i = 0; i < 4; ++i) {
        int k = q * 8 + i * 2;
        o[i] = pk2(ht[k][n], ht[k + 1][n]);
    }
    *(uint4*)(Xh + kb * 8192 + n * 32 + q * 8) = make_uint4(o[0], o[1], o[2], o[3]);
}

// ---------------------------------------------------------------------------
// K2: Y[ks] = Abf[mi-band] @ Xh  (m97 structure).  128x128 tile, 256 thr,
// 4 waves x (64x64), BK=64, global_load_lds(16B), double-buffered LDS.
// Grid 256 = 64 mi x 2 ks x 2 ni.  K per block = 4096 (KSPLIT=2).
// ---------------------------------------------------------------------------
__global__ __launch_bounds__(256) void biggemm_kernel(const unsigned short* __restrict__ Abf,
                                                      const unsigned short* __restrict__ Xh,
                                                      float* __restrict__ Ybase) {
    const int t = threadIdx.x;
    const int w = t >> 6, l = t & 63;
    const int bid = blockIdx.x;
    const int mi = bid >> 2, ks = (bid >> 1) & 1, ni = bid & 1;
    const int kbase = ks * 4096;

    __shared__ __align__(16) unsigned short lds[2][16384];   // 2 x (A 16KB + B 16KB)

    const int m16 = l & 15, q8 = (l >> 4) * 8;

    // 8 staging loads/thread/iter: 4 A frag-tiles + 4 B frag-tiles
    const unsigned short* ag[4];
    const unsigned short* bg[4];
    int aslot[4], bslot[4];
#pragma unroll
    for (int j = 0; j < 4; ++j) {
        const int idx = w * 4 + j;          // 0..15 over (w,j)
        const int ft = idx >> 1, s = idx & 1;
        ag[j] = Abf + (size_t)(mi * 128 + ft * 16 + m16) * N_ROWS + kbase + s * 32 + q8;
        aslot[j] = idx * 512;               // ushort offset; 1KB per frag-tile
        bg[j] = Xh + (size_t)((kbase >> 5) + s) * 8192
                   + (ni * 128 + ft * 16 + m16) * 32 + q8;
        bslot[j] = 8192 + idx * 512;
    }

    f32x4_t acc[4][4] = {};

    // prologue: stage iter 0 into buf 0
#pragma unroll
    for (int j = 0; j < 4; ++j) {
        gload16(ag[j], &lds[0][aslot[j]]);
        gload16(bg[j], &lds[0][bslot[j]]);
    }

    const int wm = w & 1, wn = w >> 1;
    const int KITERS = 64;                  // 4096 / 64
    for (int i = 0; i < KITERS; ++i) {
        __syncthreads();                    // drains this iter's staging loads
        const int cb = i & 1;
        if (i + 1 < KITERS) {
            const int nb = cb ^ 1;
#pragma unroll
            for (int j = 0; j < 4; ++j) {
                gload16(ag[j] + (i + 1) * 64,                 &lds[nb][aslot[j]]);
                gload16(bg[j] + (size_t)(i + 1) * 16384,      &lds[nb][bslot[j]]);
            }
        }
#pragma unroll
        for (int s = 0; s < 2; ++s) {
            bf16x8_t af[4], bf[4];
#pragma unroll
            for (int x = 0; x < 4; ++x) {
                af[x] = *(const bf16x8_t*)&lds[cb][((wm * 4 + x) * 2 + s) * 512 + l * 8];
                bf[x] = *(const bf16x8_t*)&lds[cb][8192 + ((wn * 4 + x) * 2 + s) * 512 + l * 8];
            }
#pragma unroll
            for (int x = 0; x < 4; ++x)
#pragma unroll
                for (int y = 0; y < 4; ++y)
                    acc[x][y] = __builtin_amdgcn_mfma_f32_16x16x32_bf16(af[x], bf[y], acc[x][y], 0, 0, 0);
        }
    }

    float* Y = Ybase + (size_t)ks * (N_ROWS * F_DIM);
#pragma unroll
    for (int x = 0; x < 4; ++x) {
#pragma unroll
        for (int r = 0; r < 4; ++r) {
            const int row = mi * 128 + wm * 64 + x * 16 + (l >> 4) * 4 + r;
#pragma unroll
            for (int y = 0; y < 4; ++y) {
                const int col = ni * 128 + wn * 64 + y * 16 + m16;
                Y[(size_t)row * F_DIM + col] = acc[x][y][r];
            }
        }
    }
}

// ---------------------------------------------------------------------------
// K3: out = relu( (d ∘ (Y0+Y1)) @ Ws ).  BM=32, BN=256, K=256.  512 thr,
// A staged via tiny LDS (fragment order), B frags direct from L2-hot Ws.
// ---------------------------------------------------------------------------
__global__ __launch_bounds__(512) void outgemm_kernel(const float* __restrict__ Y0,
                                                      const float* __restrict__ Y1,
                                                      const unsigned short* __restrict__ Ws,
                                                      const float* __restrict__ dvec,
                                                      float* __restrict__ out) {
    const int t   = threadIdx.x;
    const int blk = blockIdx.x;               // 32-row M tile
    const int w = t >> 6, l = t & 63;
    const int m = l & 15, q = l >> 4;

    __shared__ __align__(16) unsigned short Al[2][1024];

    const int ar = t >> 4, ac = (t & 15) * 2;
    const int arow = blk * 32 + ar;
    const float* y0p = Y0 + (size_t)arow * F_DIM + ac;
    const float* y1p = Y1 + (size_t)arow * F_DIM + ac;
    const float ds = dvec[arow];
    const int wr_idx = (ac >> 3) * 256 + (ar >> 4) * 128 + (ar & 15) * 8 + (ac & 7);

    const unsigned short* bptr = Ws + (w * 32 + m) * 32 + q * 8;

    f32x4_t acc[2][2] = {};

    float2 a_cur[2]; uint4 b_cur[2][2];
#pragma unroll
    for (int s = 0; s < 2; ++s) {
        float2 u0 = *(const float2*)(y0p + s * 32);
        float2 u1 = *(const float2*)(y1p + s * 32);
        a_cur[s] = make_float2((u0.x + u1.x) * ds, (u0.y + u1.y) * ds);
        b_cur[s][0] = *(const uint4*)(bptr + s * 8192);
        b_cur[s][1] = *(const uint4*)(bptr + s * 8192 + 512);
    }

    const int KITERS = 4;
    for (int i = 0; i < KITERS; ++i) {
        float2 a_nxt[2]; uint4 b_nxt[2][2];
        if (i + 1 < KITERS) {
            const float* p0 = y0p + (i + 1) * 64;
            const float* p1 = y1p + (i + 1) * 64;
            const unsigned short* bp = bptr + (size_t)(i + 1) * 16384;
#pragma unroll
            for (int s = 0; s < 2; ++s) {
                float2 u0 = *(const float2*)(p0 + s * 32);
                float2 u1 = *(const float2*)(p1 + s * 32);
                a_nxt[s] = make_float2((u0.x + u1.x) * ds, (u0.y + u1.y) * ds);
                b_nxt[s][0] = *(const uint4*)(bp + s * 8192);
                b_nxt[s][1] = *(const uint4*)(bp + s * 8192 + 512);
            }
        }
        const unsigned aw0 = pk2(a_cur[0].x, a_cur[0].y);
        const unsigned aw1 = pk2(a_cur[1].x, a_cur[1].y);
        __syncthreads();
        *(unsigned*)&Al[0][wr_idx] = aw0;
        *(unsigned*)&Al[1][wr_idx] = aw1;
        __syncthreads();
#pragma unroll
        for (int s = 0; s < 2; ++s) {
            bf16x8_t af0 = *(const bf16x8_t*)&Al[s][q * 256 + m * 8];
            bf16x8_t af1 = *(const bf16x8_t*)&Al[s][q * 256 + 128 + m * 8];
            bf16x8_t bf0 = __builtin_bit_cast(bf16x8_t, b_cur[s][0]);
            bf16x8_t bf1 = __builtin_bit_cast(bf16x8_t, b_cur[s][1]);
            acc[0][0] = __builtin_amdgcn_mfma_f32_16x16x32_bf16(af0, bf0, acc[0][0], 0, 0, 0);
            acc[0][1] = __builtin_amdgcn_mfma_f32_16x16x32_bf16(af0, bf1, acc[0][1], 0, 0, 0);
            acc[1][0] = __builtin_amdgcn_mfma_f32_16x16x32_bf16(af1, bf0, acc[1][0], 0, 0, 0);
            acc[1][1] = __builtin_amdgcn_mfma_f32_16x16x32_bf16(af1, bf1, acc[1][1], 0, 0, 0);
        }
#pragma unroll
        for (int s = 0; s < 2; ++s) {
            a_cur[s] = a_nxt[s];
            b_cur[s][0] = b_nxt[s][0];
            b_cur[s][1] = b_nxt[s][1];
        }
    }

    const int gcol0 = w * 32 + m;
#pragma unroll
    for (int mt = 0; mt < 2; ++mt) {
#pragma unroll
        for (int r = 0; r < 4; ++r) {
            const int grow = blk * 32 + mt * 16 + q * 4 + r;
#pragma unroll
            for (int nt = 0; nt < 2; ++nt) {
                float v = acc[mt][nt][r];
                v = fmaxf(v, 0.f);
                out[(size_t)grow * F_DIM + gcol0 + nt * 16] = v;
            }
        }
    }
}

// ---------------------------------------------------------------------------
extern "C" void kernel_launch(void* const* d_in, const int* in_sizes, int n_in,
                              void* d_out, int out_size, void* d_ws, size_t ws_size,
                              hipStream_t stream) {
    (void)in_sizes; (void)n_in; (void)out_size; (void)ws_size;
    const float* H = (const float*)d_in[0];
    const float* A = (const float*)d_in[1];
    const float* W = (const float*)d_in[2];
    float* out = (float*)d_out;

    char* ws = (char*)d_ws;
    size_t off = 0;
    float*          dvec = (float*)(ws + off);           off += (32 << 10);
    unsigned short* Xh   = (unsigned short*)(ws + off);  off += (4 << 20);
    unsigned short* Wsz  = (unsigned short*)(ws + off);  off += (128 << 10);
    float*          Y    = (float*)(ws + off);           off += (16 << 20);   // Y0 | Y1
    unsigned short* Abf  = (unsigned short*)(ws + off);  off += (size_t)N_ROWS * N_ROWS * 2;

    float* Y0 = Y;
    float* Y1 = Y + (size_t)N_ROWS * F_DIM;

    wconv_kernel  <<<dim3(8),   dim3(256),  0, stream>>>(W, Wsz);
    sumconv_kernel<<<dim3(256), dim3(1024), 0, stream>>>(A, H, dvec, Abf, Xh);
    biggemm_kernel<<<dim3(256), dim3(256),  0, stream>>>(Abf, Xh, Y);
    outgemm_kernel<<<dim3(256), dim3(512),  0, stream>>>(Y0, Y1, Wsz, dvec, out);
}

// Round 3
// 476.498 us; speedup vs baseline: 1.0875x; 1.0875x over previous
//
#include <hip/hip_runtime.h>
#include <hip/hip_bf16.h>

#define N_ROWS 8192
#define F_DIM  256
#define KSPLIT 4

typedef __bf16 bf16x8_t __attribute__((ext_vector_type(8)));
typedef float  f32x4_t  __attribute__((ext_vector_type(4)));

static __device__ __forceinline__ unsigned short f2bf(float x) {
    union { __hip_bfloat16 h; unsigned short u; } c;
    c.h = __float2bfloat16(x);   // RNE
    return c.u;
}
static __device__ __forceinline__ unsigned pk2(float lo, float hi) {
    return (unsigned)f2bf(lo) | ((unsigned)f2bf(hi) << 16);
}

// async global->LDS, 16B per lane; LDS dst = wave-uniform base + lane*16
static __device__ __forceinline__ void gload16(const unsigned short* g, unsigned short* s) {
    __builtin_amdgcn_global_load_lds((const __attribute__((address_space(1))) void*)g,
                                     (__attribute__((address_space(3))) void*)s, 16, 0, 0);
}

// ---------------------------------------------------------------------------
// K0: W [256][256] fp32 -> bf16, swizzled Ws[kb][n][kc]  (kb=k>>5, kc=k&31)
// B-fragment (lane: n=l&15, k=q*8+j) is one contiguous 16B load.
// ---------------------------------------------------------------------------
__global__ __launch_bounds__(256) void wconv_kernel(const float* __restrict__ W,
                                                    unsigned short* __restrict__ Ws) {
    const int kb = blockIdx.x;            // 8 blocks of 32 k-rows
    const int t  = threadIdx.x;
    __shared__ float wt[32][257];
    const int r = t >> 3, g = t & 7;
    const float* src = W + (kb * 32 + r) * F_DIM + g * 32;
#pragma unroll
    for (int i = 0; i < 8; ++i) {
        float4 v = *(const float4*)(src + i * 4);
        wt[r][g * 32 + i * 4 + 0] = v.x;
        wt[r][g * 32 + i * 4 + 1] = v.y;
        wt[r][g * 32 + i * 4 + 2] = v.z;
        wt[r][g * 32 + i * 4 + 3] = v.w;
    }
    __syncthreads();
    unsigned o[16];
#pragma unroll
    for (int k = 0; k < 32; k += 2) o[k >> 1] = pk2(wt[k][t], wt[k + 1][t]);
    uint4* dst = (uint4*)(Ws + kb * 8192 + t * 32);
#pragma unroll
    for (int i = 0; i < 4; ++i) dst[i] = make_uint4(o[4*i], o[4*i+1], o[4*i+2], o[4*i+3]);
}

// ---------------------------------------------------------------------------
// K1: per 32-row band: rowsum(A) -> d; write Abf = bf16(A) row-major;
// Xh = d*H -> bf16 swizzled [kb][n][kc].
// ---------------------------------------------------------------------------
__global__ __launch_bounds__(1024) void sumconv_kernel(const float* __restrict__ A,
                                                       const float* __restrict__ H,
                                                       float* __restrict__ dvec,
                                                       unsigned short* __restrict__ Abf,
                                                       unsigned short* __restrict__ Xh) {
    const int kb = blockIdx.x;            // 256 blocks, 32 rows each
    const int t  = threadIdx.x;
    __shared__ float psum[32][33];
    __shared__ float dl[32];
    __shared__ float ht[32][257];

    const int r = t >> 5, g = t & 31;     // 32 threads per row
    const int row = kb * 32 + r;
    const float* arow = A + (size_t)row * N_ROWS;
    unsigned short* aout = Abf + (size_t)row * N_ROWS;
    float s0 = 0.f, s1 = 0.f, s2 = 0.f, s3 = 0.f;
#pragma unroll 8
    for (int i = 0; i < 64; ++i) {
        const int e = (i * 32 + g) * 4;
        float4 v = *(const float4*)(arow + e);
        s0 += v.x; s1 += v.y; s2 += v.z; s3 += v.w;
        uint2 p = make_uint2(pk2(v.x, v.y), pk2(v.z, v.w));
        *(uint2*)(aout + e) = p;
    }
    psum[r][g] = (s0 + s1) + (s2 + s3);
    __syncthreads();
    if (t < 32) {
        float s = 0.f;
#pragma unroll
        for (int i = 0; i < 32; ++i) s += psum[t][i];
        float d = 1.0f / sqrtf(s);
        dl[t] = d;
        dvec[kb * 32 + t] = d;
    }
    __syncthreads();
    {   // load H band pre-scaled by d_row into LDS
        const int hr = t >> 5, hg = t & 31;
        const float* hsrc = H + (size_t)(kb * 32 + hr) * F_DIM + hg * 8;
        float4 v0 = ((const float4*)hsrc)[0];
        float4 v1 = ((const float4*)hsrc)[1];
        const float d = dl[hr];
        ht[hr][hg * 8 + 0] = v0.x * d;
        ht[hr][hg * 8 + 1] = v0.y * d;
        ht[hr][hg * 8 + 2] = v0.z * d;
        ht[hr][hg * 8 + 3] = v0.w * d;
        ht[hr][hg * 8 + 4] = v1.x * d;
        ht[hr][hg * 8 + 5] = v1.y * d;
        ht[hr][hg * 8 + 6] = v1.z * d;
        ht[hr][hg * 8 + 7] = v1.w * d;
    }
    __syncthreads();
    // transpose-read: thread -> (n = t>>2, quarter q = t&3), write 16 B
    const int n = t >> 2, q = t & 3;
    unsigned o[4];
#pragma unroll
    for (int i = 0; i < 4; ++i) {
        int k = q * 8 + i * 2;
        o[i] = pk2(ht[k][n], ht[k + 1][n]);
    }
    *(uint4*)(Xh + kb * 8192 + n * 32 + q * 8) = make_uint4(o[0], o[1], o[2], o[3]);
}

// ---------------------------------------------------------------------------
// K2: Y[ks] = Abf[mi-band] @ Xh[k-slice].  128x128 tile, 256 thr, 4 waves,
// BK=64, global_load_lds(16B), double-buffered LDS (64KB).
// Grid 512 = 64 mi x 4 ks x 2 ni  ->  2 blocks/CU (cross-block pipelining).
// K per block = 2048 (KSPLIT=4), 32 iters.
// ---------------------------------------------------------------------------
__global__ __launch_bounds__(256, 2) void biggemm_kernel(const unsigned short* __restrict__ Abf,
                                                         const unsigned short* __restrict__ Xh,
                                                         float* __restrict__ Ybase) {
    const int t = threadIdx.x;
    const int w = t >> 6, l = t & 63;
    const int bid = blockIdx.x;
    const int ni = bid & 1, ks = (bid >> 1) & 3, mi = bid >> 3;
    const int kbase = ks * 2048;

    __shared__ __align__(16) unsigned short lds[2][16384];   // 2 x (A 16KB + B 16KB)

    const int m16 = l & 15, q8 = (l >> 4) * 8;

    // 8 staging loads/thread/iter: 4 A frag-tiles + 4 B frag-tiles
    const unsigned short* ag[4];
    const unsigned short* bg[4];
    int aslot[4], bslot[4];
#pragma unroll
    for (int j = 0; j < 4; ++j) {
        const int idx = w * 4 + j;          // 0..15 over (w,j)
        const int ft = idx >> 1, s = idx & 1;
        ag[j] = Abf + (size_t)(mi * 128 + ft * 16 + m16) * N_ROWS + kbase + s * 32 + q8;
        aslot[j] = idx * 512;               // ushort offset; 1KB per frag-tile
        bg[j] = Xh + (size_t)((kbase >> 5) + s) * 8192
                   + (ni * 128 + ft * 16 + m16) * 32 + q8;
        bslot[j] = 8192 + idx * 512;
    }

    f32x4_t acc[4][4] = {};

    // prologue: stage iter 0 into buf 0
#pragma unroll
    for (int j = 0; j < 4; ++j) {
        gload16(ag[j], &lds[0][aslot[j]]);
        gload16(bg[j], &lds[0][bslot[j]]);
    }

    const int wm = w & 1, wn = w >> 1;
    const int KITERS = 2048 / 64;           // 32
    for (int i = 0; i < KITERS; ++i) {
        __syncthreads();                    // drains this iter's staging loads
        const int cb = i & 1;
        if (i + 1 < KITERS) {
            const int nb = cb ^ 1;
#pragma unroll
            for (int j = 0; j < 4; ++j) {
                gload16(ag[j] + (i + 1) * 64,            &lds[nb][aslot[j]]);
                gload16(bg[j] + (size_t)(i + 1) * 16384, &lds[nb][bslot[j]]);
            }
        }
#pragma unroll
        for (int s = 0; s < 2; ++s) {
            bf16x8_t af[4], bf[4];
#pragma unroll
            for (int x = 0; x < 4; ++x) {
                af[x] = *(const bf16x8_t*)&lds[cb][((wm * 4 + x) * 2 + s) * 512 + l * 8];
                bf[x] = *(const bf16x8_t*)&lds[cb][8192 + ((wn * 4 + x) * 2 + s) * 512 + l * 8];
            }
#pragma unroll
            for (int x = 0; x < 4; ++x)
#pragma unroll
                for (int y = 0; y < 4; ++y)
                    acc[x][y] = __builtin_amdgcn_mfma_f32_16x16x32_bf16(af[x], bf[y], acc[x][y], 0, 0, 0);
        }
    }

    float* Y = Ybase + (size_t)ks * (N_ROWS * F_DIM);
#pragma unroll
    for (int x = 0; x < 4; ++x) {
#pragma unroll
        for (int r = 0; r < 4; ++r) {
            const int row = mi * 128 + wm * 64 + x * 16 + (l >> 4) * 4 + r;
#pragma unroll
            for (int y = 0; y < 4; ++y) {
                const int col = ni * 128 + wn * 64 + y * 16 + m16;
                Y[(size_t)row * F_DIM + col] = acc[x][y][r];
            }
        }
    }
}

// ---------------------------------------------------------------------------
// K3: out = relu( (d ∘ ΣY_k) @ Ws ).  BM=32, BN=256, K=256.  512 thr,
// A staged via tiny LDS (fragment order), B frags direct from L2-hot Ws.
// ---------------------------------------------------------------------------
__global__ __launch_bounds__(512) void outgemm_kernel(const float* __restrict__ Ybase,
                                                      const unsigned short* __restrict__ Ws,
                                                      const float* __restrict__ dvec,
                                                      float* __restrict__ out) {
    const int t   = threadIdx.x;
    const int blk = blockIdx.x;               // 32-row M tile
    const int w = t >> 6, l = t & 63;
    const int m = l & 15, q = l >> 4;

    __shared__ __align__(16) unsigned short Al[2][1024];

    const int ar = t >> 4, ac = (t & 15) * 2;
    const int arow = blk * 32 + ar;
    const float* yp = Ybase + (size_t)arow * F_DIM + ac;
    const float ds = dvec[arow];
    const int wr_idx = (ac >> 3) * 256 + (ar >> 4) * 128 + (ar & 15) * 8 + (ac & 7);

    const unsigned short* bptr = Ws + (w * 32 + m) * 32 + q * 8;
    const size_t YS = (size_t)N_ROWS * F_DIM;

    f32x4_t acc[2][2] = {};

    float2 a_cur[2]; uint4 b_cur[2][2];
#pragma unroll
    for (int s = 0; s < 2; ++s) {
        float sx = 0.f, sy = 0.f;
#pragma unroll
        for (int k = 0; k < KSPLIT; ++k) {
            float2 u = *(const float2*)(yp + k * YS + s * 32);
            sx += u.x; sy += u.y;
        }
        a_cur[s] = make_float2(sx * ds, sy * ds);
        b_cur[s][0] = *(const uint4*)(bptr + s * 8192);
        b_cur[s][1] = *(const uint4*)(bptr + s * 8192 + 512);
    }

    const int KITERS = 4;
    for (int i = 0; i < KITERS; ++i) {
        float2 a_nxt[2]; uint4 b_nxt[2][2];
        if (i + 1 < KITERS) {
            const float* p = yp + (i + 1) * 64;
            const unsigned short* bp = bptr + (size_t)(i + 1) * 16384;
#pragma unroll
            for (int s = 0; s < 2; ++s) {
                float sx = 0.f, sy = 0.f;
#pragma unroll
                for (int k = 0; k < KSPLIT; ++k) {
                    float2 u = *(const float2*)(p + k * YS + s * 32);
                    sx += u.x; sy += u.y;
                }
                a_nxt[s] = make_float2(sx * ds, sy * ds);
                b_nxt[s][0] = *(const uint4*)(bp + s * 8192);
                b_nxt[s][1] = *(const uint4*)(bp + s * 8192 + 512);
            }
        }
        const unsigned aw0 = pk2(a_cur[0].x, a_cur[0].y);
        const unsigned aw1 = pk2(a_cur[1].x, a_cur[1].y);
        __syncthreads();
        *(unsigned*)&Al[0][wr_idx] = aw0;
        *(unsigned*)&Al[1][wr_idx] = aw1;
        __syncthreads();
#pragma unroll
        for (int s = 0; s < 2; ++s) {
            bf16x8_t af0 = *(const bf16x8_t*)&Al[s][q * 256 + m * 8];
            bf16x8_t af1 = *(const bf16x8_t*)&Al[s][q * 256 + 128 + m * 8];
            bf16x8_t bf0 = __builtin_bit_cast(bf16x8_t, b_cur[s][0]);
            bf16x8_t bf1 = __builtin_bit_cast(bf16x8_t, b_cur[s][1]);
            acc[0][0] = __builtin_amdgcn_mfma_f32_16x16x32_bf16(af0, bf0, acc[0][0], 0, 0, 0);
            acc[0][1] = __builtin_amdgcn_mfma_f32_16x16x32_bf16(af0, bf1, acc[0][1], 0, 0, 0);
            acc[1][0] = __builtin_amdgcn_mfma_f32_16x16x32_bf16(af1, bf0, acc[1][0], 0, 0, 0);
            acc[1][1] = __builtin_amdgcn_mfma_f32_16x16x32_bf16(af1, bf1, acc[1][1], 0, 0, 0);
        }
#pragma unroll
        for (int s = 0; s < 2; ++s) {
            a_cur[s] = a_nxt[s];
            b_cur[s][0] = b_nxt[s][0];
            b_cur[s][1] = b_nxt[s][1];
        }
    }

    const int gcol0 = w * 32 + m;
#pragma unroll
    for (int mt = 0; mt < 2; ++mt) {
#pragma unroll
        for (int r = 0; r < 4; ++r) {
            const int grow = blk * 32 + mt * 16 + q * 4 + r;
#pragma unroll
            for (int nt = 0; nt < 2; ++nt) {
                float v = acc[mt][nt][r];
                v = fmaxf(v, 0.f);
                out[(size_t)grow * F_DIM + gcol0 + nt * 16] = v;
            }
        }
    }
}

// ---------------------------------------------------------------------------
extern "C" void kernel_launch(void* const* d_in, const int* in_sizes, int n_in,
                              void* d_out, int out_size, void* d_ws, size_t ws_size,
                              hipStream_t stream) {
    (void)in_sizes; (void)n_in; (void)out_size; (void)ws_size;
    const float* H = (const float*)d_in[0];
    const float* A = (const float*)d_in[1];
    const float* W = (const float*)d_in[2];
    float* out = (float*)d_out;

    char* ws = (char*)d_ws;
    size_t off = 0;
    float*          dvec = (float*)(ws + off);           off += (32 << 10);
    unsigned short* Xh   = (unsigned short*)(ws + off);  off += (4 << 20);
    unsigned short* Wsz  = (unsigned short*)(ws + off);  off += (128 << 10);
    float*          Y    = (float*)(ws + off);           off += (size_t)KSPLIT * N_ROWS * F_DIM * 4;
    unsigned short* Abf  = (unsigned short*)(ws + off);  off += (size_t)N_ROWS * N_ROWS * 2;

    wconv_kernel  <<<dim3(8),   dim3(256),  0, stream>>>(W, Wsz);
    sumconv_kernel<<<dim3(256), dim3(1024), 0, stream>>>(A, H, dvec, Abf, Xh);
    biggemm_kernel<<<dim3(512), dim3(256),  0, stream>>>(Abf, Xh, Y);
    outgemm_kernel<<<dim3(256), dim3(512),  0, stream>>>(Y, Wsz, dvec, out);
}